// Round 18
// baseline (1040.761 us; speedup 1.0000x reference)
//
#include <hip/hip_runtime.h>
#include <hip/hip_bf16.h>
#include <stdint.h>

#define S 2048
#define D 768
#define H 12
#define HD 64
#define V 32000
#define R 32
#define DFF 3072
#define NLAYERS 4
#define EPS 1e-6f

typedef __bf16 bf16;
typedef __bf16 bf16x4 __attribute__((ext_vector_type(4)));
typedef __bf16 bf16x8 __attribute__((ext_vector_type(8)));
typedef float f32x4 __attribute__((ext_vector_type(4)));

// 1D grid, XCD-bijective swizzle (nwg % 8 == 0 for all grids), M-fastest so
// consecutive logical blocks share one B-panel (L2 reuse).
__device__ __forceinline__ int swz_logical(int nwg) {
    int id = blockIdx.x;
    int q = nwg >> 3;
    return (id & 7) * q + (id >> 3);
}

// ---------------- fp32 -> bf16 conversion ----------------
__global__ __launch_bounds__(256) void k_cvt(const float* __restrict__ in,
                                             bf16* __restrict__ out, long n) {
    long i = ((long)blockIdx.x * 256 + threadIdx.x) * 4;
    if (i >= n) return;
    float4 v = *(const float4*)(in + i);
    bf16x4 o;
    o.x = (bf16)v.x; o.y = (bf16)v.y; o.z = (bf16)v.z; o.w = (bf16)v.w;
    *(bf16x4*)(out + i) = o;
}

// ---- LoRA fold (A staged in LDS): Wb[n,k] = bf16(W[n,k] + (1/R)*sum_r A[k,r]*B[r,n])
__global__ __launch_bounds__(256) void k_fold(const float* __restrict__ W,
                                              const float* __restrict__ A,
                                              const float* __restrict__ B,
                                              bf16* __restrict__ Wb,
                                              int N, int K) {
    __shared__ float As[256][33];   // [k_local][r], +1 pad
    int l = blockIdx.z;
    const float* Wl = W + (long)l * N * K;
    const float* Al = A + (long)l * K * R;
    const float* Bl = B + (long)l * R * N;
    bf16* Wbl = Wb + (long)l * N * K;
    int t = threadIdx.x;
    long k0 = (long)blockIdx.x * 256;
    int n0 = blockIdx.y * 8;
    const float* Ab = Al + k0 * R;
    #pragma unroll
    for (int i = 0; i < 32; ++i) {
        int idx = i * 256 + t;
        As[idx >> 5][idx & 31] = Ab[idx];
    }
    __syncthreads();
    long k = k0 + t;
    float acc[8];
    #pragma unroll
    for (int j = 0; j < 8; ++j) acc[j] = Wl[(long)(n0 + j) * K + k];
    for (int r = 0; r < R; ++r) {
        float a = As[t][r] * (1.0f / R);
        #pragma unroll
        for (int j = 0; j < 8; ++j)
            acc[j] = fmaf(a, Bl[(long)r * N + n0 + j], acc[j]);
    }
    #pragma unroll
    for (int j = 0; j < 8; ++j) Wbl[(long)(n0 + j) * K + k] = (bf16)acc[j];
}

// ---------------- embedding gather ----------------
__global__ void k_embed(const int* __restrict__ ids, const float* __restrict__ emb,
                        float* __restrict__ x) {
    int s = blockIdx.x;
    int row = ids[s];
    for (int d = threadIdx.x; d < D; d += blockDim.x)
        x[s * D + d] = emb[row * D + d];
}

// ---------------- layernorm -> bf16, one WAVE per row, no barriers ----------
__global__ __launch_bounds__(256) void k_ln_bf(const float* __restrict__ x,
                                               const float* __restrict__ g,
                                               const float* __restrict__ b,
                                               bf16* __restrict__ out) {
    int w = threadIdx.x >> 6, lane = threadIdx.x & 63;
    long s = (long)blockIdx.x * 4 + w;
    const float* xr = x + s * D;
    float4 v0 = *(const float4*)(xr + lane * 4);
    float4 v1 = *(const float4*)(xr + 256 + lane * 4);
    float4 v2 = *(const float4*)(xr + 512 + lane * 4);
    float sum = v0.x + v0.y + v0.z + v0.w + v1.x + v1.y + v1.z + v1.w
              + v2.x + v2.y + v2.z + v2.w;
    float sq = v0.x*v0.x + v0.y*v0.y + v0.z*v0.z + v0.w*v0.w
             + v1.x*v1.x + v1.y*v1.y + v1.z*v1.z + v1.w*v1.w
             + v2.x*v2.x + v2.y*v2.y + v2.z*v2.z + v2.w*v2.w;
    #pragma unroll
    for (int m = 1; m < 64; m <<= 1) {
        sum += __shfl_xor(sum, m);
        sq  += __shfl_xor(sq, m);
    }
    float mean = sum * (1.0f / D);
    float var  = sq * (1.0f / D) - mean * mean;
    float rs = rsqrtf(var + EPS);
    bf16* orow = out + s * D;
    #pragma unroll
    for (int j = 0; j < 3; ++j) {
        float4 v = (j == 0) ? v0 : (j == 1) ? v1 : v2;
        float4 gv = *(const float4*)(g + j * 256 + lane * 4);
        float4 bv = *(const float4*)(b + j * 256 + lane * 4);
        bf16x4 o;
        o[0] = (bf16)((v.x - mean) * rs * gv.x + bv.x);
        o[1] = (bf16)((v.y - mean) * rs * gv.y + bv.y);
        o[2] = (bf16)((v.z - mean) * rs * gv.z + bv.z);
        o[3] = (bf16)((v.w - mean) * rs * gv.w + bv.w);
        *(bf16x4*)(orow + j * 256 + lane * 4) = o;
    }
}

// ---------------- shared GEMM machinery ----------------
__device__ __forceinline__ void gload16(const bf16* g, bf16* l) {
    __builtin_amdgcn_global_load_lds(
        (const __attribute__((address_space(1))) void*)g,
        (__attribute__((address_space(3))) void*)l, 16, 0, 0);
}

// lm_head GEMM: 128x128 tile, BK=32, conflict-free swizzle + T3-min
// prefetch-ahead double buffer (r16-proven: 162us, occ 39%, 0 conflicts).
__global__ __launch_bounds__(256) void k_gemm_lm(const bf16* __restrict__ X,
                                                 const bf16* __restrict__ W,
                                                 float* __restrict__ C,
                                                 int N, int K, int nwg) {
    __shared__ bf16 At[2][128 * 32];
    __shared__ bf16 Bt[2][128 * 32];
    int tid = threadIdx.x;
    int w = tid >> 6, lane = tid & 63;
    int logical = swz_logical(nwg);
    long m0 = (long)(logical & 15) * 128;
    long n0 = (long)(logical >> 4) * 128;
    int wr = (w >> 1) * 64, wc = (w & 1) * 64;
    int fr = lane & 15;
    int g  = lane >> 4;
    f32x4 acc[4][4] = {};

#define STAGE_LM(K0, BUF) do {                                             \
    _Pragma("unroll")                                                      \
    for (int i = 0; i < 2; ++i) {                                          \
        int ci = tid + 256 * i;                                            \
        int r = ci >> 2, c = (ci & 3) ^ ((r >> 1) & 3);                    \
        gload16(X + (m0 + r) * K + (K0) + c * 8, At[BUF] + ci * 8);        \
        gload16(W + (n0 + r) * K + (K0) + c * 8, Bt[BUF] + ci * 8);        \
    } } while (0)

    STAGE_LM(0, 0);
    __syncthreads();
    int cur = 0;
    for (int k0 = 0; k0 < K; k0 += 32) {
        if (k0 + 32 < K) STAGE_LM(k0 + 32, cur ^ 1);
        bf16x8 a[4], b[4];
        #pragma unroll
        for (int m = 0; m < 4; m++) {
            int row = wr + m * 16 + fr;
            a[m] = *(const bf16x8*)(At[cur] + row * 32 + ((g ^ ((row >> 1) & 3)) * 8));
        }
        #pragma unroll
        for (int n = 0; n < 4; n++) {
            int row = wc + n * 16 + fr;
            b[n] = *(const bf16x8*)(Bt[cur] + row * 32 + ((g ^ ((row >> 1) & 3)) * 8));
        }
        #pragma unroll
        for (int m = 0; m < 4; m++)
            #pragma unroll
            for (int n = 0; n < 4; n++)
                acc[m][n] = __builtin_amdgcn_mfma_f32_16x16x32_bf16(a[m], b[n], acc[m][n], 0, 0, 0);
        __syncthreads();
        cur ^= 1;
    }
#undef STAGE_LM
    int cr = (lane >> 4) * 4, cc = lane & 15;
    #pragma unroll
    for (int m = 0; m < 4; m++)
        #pragma unroll
        for (int n = 0; n < 4; n++) {
            long col = n0 + wc + n * 16 + cc;
            #pragma unroll
            for (int r = 0; r < 4; r++) {
                long idx = (m0 + wr + m * 16 + cr + r) * N + col;
                C[idx] = acc[m][n][r];
            }
        }
}

// 32x128 tile small-N GEMM (out-proj, fc2): r15-proven single-buffer config
// (384 blocks, BK=64 XOR swizzle, 20 KB LDS -> 8 blocks/CU). Always RESID.
template <int TAG>
__global__ __launch_bounds__(256) void k_gemm_small(const bf16* __restrict__ X,
                                                    const bf16* __restrict__ W,
                                                    float* __restrict__ C,
                                                    int N, int K,
                                                    const float* __restrict__ ls,
                                                    int nwg) {
    __shared__ bf16 At[32 * 64];        // 4 KB
    __shared__ bf16 Bt[128 * 64];       // 16 KB
    int tid = threadIdx.x;
    int w = tid >> 6, lane = tid & 63;
    int logical = swz_logical(nwg);
    long m0 = (long)(logical & 63) * 32;
    long n0 = (long)(logical >> 6) * 128;
    int wr = (w >> 1) * 16, wc = (w & 1) * 64;
    int fr = lane & 15;
    int g  = lane >> 4;
    f32x4 acc[4] = {};
    for (int k0 = 0; k0 < K; k0 += 64) {
        {
            int ci = tid;
            int r = ci >> 3, c = (ci & 7) ^ (r & 7);
            gload16(X + (m0 + r) * K + k0 + c * 8, At + ci * 8);
        }
        #pragma unroll
        for (int i = 0; i < 4; ++i) {
            int ci = tid + 256 * i;
            int r = ci >> 3, c = (ci & 7) ^ (r & 7);
            gload16(W + (n0 + r) * K + k0 + c * 8, Bt + ci * 8);
        }
        __syncthreads();
        #pragma unroll
        for (int kk = 0; kk < 2; ++kk) {
            bf16x8 a, b[4];
            {
                int row = wr + fr;
                a = *(const bf16x8*)(At + row * 64 + (((kk * 4 + g) ^ (row & 7)) * 8));
            }
            #pragma unroll
            for (int n = 0; n < 4; n++) {
                int row = wc + n * 16 + fr;
                b[n] = *(const bf16x8*)(Bt + row * 64 + (((kk * 4 + g) ^ (row & 7)) * 8));
            }
            #pragma unroll
            for (int n = 0; n < 4; n++)
                acc[n] = __builtin_amdgcn_mfma_f32_16x16x32_bf16(a, b[n], acc[n], 0, 0, 0);
        }
        __syncthreads();
    }
    int cr = (lane >> 4) * 4, cc = lane & 15;
    #pragma unroll
    for (int n = 0; n < 4; n++) {
        long col = n0 + wc + n * 16 + cc;
        #pragma unroll
        for (int r = 0; r < 4; r++) {
            long idx = (m0 + wr + cr + r) * N + col;
            C[idx] = fmaf(ls[col], acc[n][r], C[idx]);
        }
    }
}

// qkv GEMM, 64x128 tile, BK=64 swizzled + T3-min prefetch-ahead dbuf
// (48 KB LDS, flat array + offset macros — no LDS pointer initializers).
__global__ __launch_bounds__(256) void k_gemm_qkv(const bf16* __restrict__ X,
                                                  const bf16* __restrict__ W,
                                                  bf16* __restrict__ Qh,
                                                  bf16* __restrict__ Kh,
                                                  bf16* __restrict__ Vt,
                                                  int nwg) {
    const int K = D;
    __shared__ bf16 smem[2 * (64 * 64 + 128 * 64)];   // 48 KB
#define QKV_AT(B) (smem + (B) * (64 * 64))
#define QKV_BT(B) (smem + 2 * (64 * 64) + (B) * (128 * 64))
    int tid = threadIdx.x;
    int w = tid >> 6, lane = tid & 63;
    int logical = swz_logical(nwg);
    long m0 = (long)(logical & 31) * 64;
    long n0 = (long)(logical >> 5) * 128;
    int wr = (w >> 1) * 32, wc = (w & 1) * 64;
    int fr = lane & 15;
    int g  = lane >> 4;
    f32x4 acc[2][4] = {};

#define STAGE_QKV(K0, BUF) do {                                            \
    _Pragma("unroll")                                                      \
    for (int i = 0; i < 2; ++i) {                                          \
        int ci = tid + 256 * i;                                            \
        int r = ci >> 3, c = (ci & 7) ^ (r & 7);                           \
        gload16(X + (m0 + r) * K + (K0) + c * 8, QKV_AT(BUF) + ci * 8);    \
    }                                                                      \
    _Pragma("unroll")                                                      \
    for (int i = 0; i < 4; ++i) {                                          \
        int ci = tid + 256 * i;                                            \
        int r = ci >> 3, c = (ci & 7) ^ (r & 7);                           \
        gload16(W + (n0 + r) * K + (K0) + c * 8, QKV_BT(BUF) + ci * 8);    \
    } } while (0)

    STAGE_QKV(0, 0);
    __syncthreads();
    int cur = 0;
    for (int k0 = 0; k0 < K; k0 += 64) {
        if (k0 + 64 < K) STAGE_QKV(k0 + 64, cur ^ 1);
        const bf16* At = QKV_AT(cur);
        const bf16* Bt = QKV_BT(cur);
        #pragma unroll
        for (int kk = 0; kk < 2; ++kk) {
            bf16x8 a[2], b[4];
            #pragma unroll
            for (int m = 0; m < 2; m++) {
                int row = wr + m * 16 + fr;
                a[m] = *(const bf16x8*)(At + row * 64 + (((kk * 4 + g) ^ (row & 7)) * 8));
            }
            #pragma unroll
            for (int n = 0; n < 4; n++) {
                int row = wc + n * 16 + fr;
                b[n] = *(const bf16x8*)(Bt + row * 64 + (((kk * 4 + g) ^ (row & 7)) * 8));
            }
            #pragma unroll
            for (int m = 0; m < 2; m++)
                #pragma unroll
                for (int n = 0; n < 4; n++)
                    acc[m][n] = __builtin_amdgcn_mfma_f32_16x16x32_bf16(a[m], b[n], acc[m][n], 0, 0, 0);
        }
        __syncthreads();
        cur ^= 1;
    }
#undef STAGE_QKV
#undef QKV_AT
#undef QKV_BT
    int cr = (lane >> 4) * 4, cc = lane & 15;
    if (n0 < 1536) {
        // ---- Q or K: stage [s][col] in LDS ([64][136]), coalesced store ----
        float scale = (n0 < 768) ? 0.125f : 1.0f;
        bf16* dst = (n0 < 768) ? Qh : Kh;
        int base = (n0 < 768) ? (int)n0 : (int)n0 - 768;
        #pragma unroll
        for (int m = 0; m < 2; m++)
            #pragma unroll
            for (int n = 0; n < 4; n++)
                #pragma unroll
                for (int r = 0; r < 4; r++)
                    smem[(wr + m * 16 + cr + r) * 136 + wc + n * 16 + cc] =
                        (bf16)(acc[m][n][r] * scale);
        __syncthreads();
        #pragma unroll
        for (int i = 0; i < 4; ++i) {
            int c = tid + 256 * i;
            int srow = c >> 4, off = (c & 15) * 8;
            int hh = (base >> 6) + (off >> 6);
            int d0 = off & 63;
            bf16x8 vv = *(const bf16x8*)(smem + srow * 136 + off);
            *(bf16x8*)(dst + ((long)hh * S + m0 + srow) * HD + d0) = vv;
        }
    } else {
        // ---- V: stage TRANSPOSED [col][s] in LDS ([128][72]), coalesced ----
        int base = (int)n0 - 1536;
        #pragma unroll
        for (int m = 0; m < 2; m++)
            #pragma unroll
            for (int n = 0; n < 4; n++) {
                bf16x4 pv;
                #pragma unroll
                for (int r = 0; r < 4; ++r) pv[r] = (bf16)acc[m][n][r];
                *(bf16x4*)(smem + (wc + n * 16 + cc) * 72 + wr + m * 16 + cr) = pv;
            }
        __syncthreads();
        #pragma unroll
        for (int i = 0; i < 4; ++i) {
            int c = tid + 256 * i;
            int vcol = c >> 3, soff = (c & 7) * 8;
            bf16x8 vv = *(const bf16x8*)(smem + vcol * 72 + soff);
            *(bf16x8*)(Vt + (long)(base + vcol) * S + m0 + soff) = vv;
        }
    }
}

// fc1 GEMM, 64x128 tile, BK=64 swizzled, dual-B, fused SwiGLU (r13-proven).
__global__ __launch_bounds__(256) void k_gemm_fc1(const bf16* __restrict__ X,
                                                  const bf16* __restrict__ W,
                                                  bf16* __restrict__ hb,
                                                  int nwg) {
    const int K = D;
    __shared__ bf16 At[64 * 64];        // 8 KB
    __shared__ bf16 Bg[128 * 64];       // 16 KB
    __shared__ bf16 Ba[128 * 64];       // 16 KB
    int tid = threadIdx.x;
    int w = tid >> 6, lane = tid & 63;
    int logical = swz_logical(nwg);
    long m0 = (long)(logical & 31) * 64;
    long f0 = (long)(logical >> 5) * 128;
    int wr = (w >> 1) * 32, wc = (w & 1) * 64;
    int fr = lane & 15;
    int g  = lane >> 4;
    const bf16* Wg = W + f0 * K;
    const bf16* Wa = W + ((long)DFF + f0) * K;
    f32x4 accG[2][4] = {}, accA[2][4] = {};
    for (int k0 = 0; k0 < K; k0 += 64) {
        #pragma unroll
        for (int i = 0; i < 2; ++i) {
            int ci = tid + 256 * i;
            int r = ci >> 3, c = (ci & 7) ^ (r & 7);
            gload16(X + (m0 + r) * K + k0 + c * 8, At + ci * 8);
        }
        #pragma unroll
        for (int i = 0; i < 4; ++i) {
            int ci = tid + 256 * i;
            int r = ci >> 3, c = (ci & 7) ^ (r & 7);
            gload16(Wg + (long)r * K + k0 + c * 8, Bg + ci * 8);
            gload16(Wa + (long)r * K + k0 + c * 8, Ba + ci * 8);
        }
        __syncthreads();
        #pragma unroll
        for (int kk = 0; kk < 2; ++kk) {
            bf16x8 a[2], bg[4], ba[4];
            #pragma unroll
            for (int m = 0; m < 2; m++) {
                int row = wr + m * 16 + fr;
                a[m] = *(const bf16x8*)(At + row * 64 + (((kk * 4 + g) ^ (row & 7)) * 8));
            }
            #pragma unroll
            for (int n = 0; n < 4; n++) {
                int row = wc + n * 16 + fr;
                int off = row * 64 + (((kk * 4 + g) ^ (row & 7)) * 8);
                bg[n] = *(const bf16x8*)(Bg + off);
                ba[n] = *(const bf16x8*)(Ba + off);
            }
            #pragma unroll
            for (int m = 0; m < 2; m++)
                #pragma unroll
                for (int n = 0; n < 4; n++) {
                    accG[m][n] = __builtin_amdgcn_mfma_f32_16x16x32_bf16(a[m], bg[n], accG[m][n], 0, 0, 0);
                    accA[m][n] = __builtin_amdgcn_mfma_f32_16x16x32_bf16(a[m], ba[n], accA[m][n], 0, 0, 0);
                }
        }
        __syncthreads();
    }
    int cr = (lane >> 4) * 4, cc = lane & 15;
    #pragma unroll
    for (int m = 0; m < 2; m++)
        #pragma unroll
        for (int n = 0; n < 4; n++) {
            long col = f0 + wc + n * 16 + cc;
            #pragma unroll
            for (int r = 0; r < 4; r++) {
                long s = m0 + wr + m * 16 + cr + r;
                float gv = accG[m][n][r], av = accA[m][n][r];
                float sig = 1.0f / (1.0f + __expf(-gv));
                hb[s * DFF + col] = (bf16)(gv * sig * av);
            }
        }
}

// ---------------- flash attention, MFMA, ALiBi+causal (round-7 proven) -----
__global__ __launch_bounds__(256) void k_attn_mfma(const bf16* __restrict__ Qh,
                                                   const bf16* __restrict__ Kh,
                                                   const bf16* __restrict__ Vt,
                                                   const float* __restrict__ slopes,
                                                   bf16* __restrict__ ao) {
    __shared__ bf16 Kl[128 * 64];
    __shared__ bf16 Vl[64 * 128];
    __shared__ bf16 Pl[4][16 * 136];
    int tid = threadIdx.x;
    int w = tid >> 6, lane = tid & 63;
    int fr = lane & 15, g = lane >> 4;
    int qb = gridDim.x - 1 - blockIdx.x;
    int q0 = qb * 64;
    int h = blockIdx.y;
    int ntiles = qb / 2 + 1;
    float slope = slopes[h];

    const bf16* qrow = Qh + ((long)h * S + q0 + w * 16 + fr) * HD;
    bf16x8 qf0 = *(const bf16x8*)(qrow + g * 8);
    bf16x8 qf1 = *(const bf16x8*)(qrow + 32 + g * 8);

    const bf16* Kg = Kh + (long)h * S * HD;
    const bf16* Vg = Vt + (long)h * HD * S;

    float m = -1e9f, l = 0.f;
    f32x4 o[4] = {};
    int qg = q0 + w * 16 + fr;

    for (int t = 0; t < ntiles; ++t) {
        int j0 = t * 128;
        __syncthreads();
        #pragma unroll
        for (int i = 0; i < 4; ++i) {
            int ci = tid + 256 * i;
            int r = ci >> 3, c = (ci & 7) ^ (r & 7);
            gload16(Kg + (long)(j0 + r) * HD + c * 8, Kl + ci * 8);
        }
        #pragma unroll
        for (int i = 0; i < 4; ++i) {
            int ci = tid + 256 * i;
            int rd = ci >> 4, cj = (ci & 15) ^ (rd & 7);
            gload16(Vg + (long)rd * S + j0 + cj * 8, Vl + ci * 8);
        }
        __syncthreads();

        f32x4 sc[8];
        __builtin_amdgcn_s_setprio(1);
        #pragma unroll
        for (int jt = 0; jt < 8; ++jt) {
            int jr = jt * 16 + fr;
            bf16x8 kf0 = *(const bf16x8*)(Kl + jr * 64 + ((g ^ (jr & 7)) * 8));
            bf16x8 kf1 = *(const bf16x8*)(Kl + jr * 64 + (((g + 4) ^ (jr & 7)) * 8));
            f32x4 z = {};
            z = __builtin_amdgcn_mfma_f32_16x16x32_bf16(kf0, qf0, z, 0, 0, 0);
            z = __builtin_amdgcn_mfma_f32_16x16x32_bf16(kf1, qf1, z, 0, 0, 0);
            sc[jt] = z;
        }
        __builtin_amdgcn_s_setprio(0);

        bool need_mask = (j0 + 127) > (q0 + w * 16);
        float mt = -1e9f;
        if (need_mask) {
            #pragma unroll
            for (int jt = 0; jt < 8; ++jt)
                #pragma unroll
                for (int r = 0; r < 4; ++r) {
                    int rel = (j0 + jt * 16 + g * 4 + r) - qg;
                    float v = (rel <= 0) ? fmaf(slope, (float)rel, sc[jt][r]) : -1e9f;
                    sc[jt][r] = v;
                    mt = fmaxf(mt, v);
                }
        } else {
            #pragma unroll
            for (int jt = 0; jt < 8; ++jt)
                #pragma unroll
                for (int r = 0; r < 4; ++r) {
                    int rel = (j0 + jt * 16 + g * 4 + r) - qg;
                    float v = fmaf(slope, (float)rel, sc[jt][r]);
                    sc[jt][r] = v;
                    mt = fmaxf(mt, v);
                }
        }
        mt = fmaxf(mt, __shfl_xor(mt, 16));
        mt = fmaxf(mt, __shfl_xor(mt, 32));
        float mnew = fmaxf(m, mt);
        float factor = __expf(m - mnew);
        float psum = 0.f;
        #pragma unroll
        for (int jt = 0; jt < 8; ++jt) {
            bf16x4 pb;
            #pragma unroll
            for (int r = 0; r < 4; ++r) {
                float p = __expf(sc[jt][r] - mnew);
                psum += p;
                pb[r] = (bf16)p;
            }
            *(bf16x4*)(&Pl[w][fr * 136 + jt * 16 + g * 4]) = pb;
        }
        psum += __shfl_xor(psum, 16);
        psum += __shfl_xor(psum, 32);
        l = l * factor + psum;
        m = mnew;
        #pragma unroll
        for (int dt = 0; dt < 4; ++dt)
            #pragma unroll
            for (int r = 0; r < 4; ++r) o[dt][r] *= factor;

        bf16x8 pf[4];
        #pragma unroll
        for (int ks = 0; ks < 4; ++ks)
            pf[ks] = *(const bf16x8*)(&Pl[w][fr * 136 + ks * 32 + g * 8]);
        __builtin_amdgcn_s_setprio(1);
        #pragma unroll
        for (int dt = 0; dt < 4; ++dt) {
            int dr = dt * 16 + fr;
            #pragma unroll
            for (int ks = 0; ks < 4; ++ks) {
                bf16x8 vf = *(const bf16x8*)(Vl + dr * 128 + (((ks * 4 + g) ^ (dr & 7)) * 8));
                o[dt] = __builtin_amdgcn_mfma_f32_16x16x32_bf16(vf, pf[ks], o[dt], 0, 0, 0);
            }
        }
        __builtin_amdgcn_s_setprio(0);
    }
    float inv = 1.0f / l;
    bf16* orow = ao + ((long)(q0 + w * 16 + fr)) * D + h * HD;
    #pragma unroll
    for (int dt = 0; dt < 4; ++dt) {
        bf16x4 ob;
        #pragma unroll
        for (int r = 0; r < 4; ++r) ob[r] = (bf16)(o[dt][r] * inv);
        *(bf16x4*)(orow + dt * 16 + g * 4) = ob;
    }
}

extern "C" void kernel_launch(void* const* d_in, const int* in_sizes, int n_in,
                              void* d_out, int out_size, void* d_ws, size_t ws_size,
                              hipStream_t stream) {
    const int*   ids    = (const int*)d_in[0];
    const float* emb    = (const float*)d_in[1];
    const float* slopes = (const float*)d_in[2];
    const float* ln1_g  = (const float*)d_in[3];
    const float* ln1_b  = (const float*)d_in[4];
    const float* qkv_W  = (const float*)d_in[5];
    const float* qkv_A  = (const float*)d_in[6];
    const float* qkv_B  = (const float*)d_in[7];
    const float* out_W  = (const float*)d_in[8];
    const float* out_A  = (const float*)d_in[9];
    const float* out_B  = (const float*)d_in[10];
    const float* ln2_g  = (const float*)d_in[11];
    const float* ln2_b  = (const float*)d_in[12];
    const float* fc1_W  = (const float*)d_in[13];
    const float* fc1_A  = (const float*)d_in[14];
    const float* fc1_B  = (const float*)d_in[15];
    const float* fc2_W  = (const float*)d_in[16];
    const float* fc2_A  = (const float*)d_in[17];
    const float* fc2_B  = (const float*)d_in[18];
    const float* ls1    = (const float*)d_in[19];
    const float* ls2    = (const float*)d_in[20];
    const float* lnf_g  = (const float*)d_in[21];
    const float* lnf_b  = (const float*)d_in[22];

    // ---- workspace layout ----
    char* p = (char*)d_ws;
    float* x      = (float*)p;               p += (long)S * D * 4;
    bf16* h_bf    = (bf16*)p;                p += (long)S * D * 2;
    bf16* ao_bf   = (bf16*)p;                p += (long)S * D * 2;
    bf16* hid_bf  = (bf16*)p;                p += (long)S * DFF * 2;
    bf16* Qh      = (bf16*)p;                p += (long)H * S * HD * 2;
    bf16* Kh      = (bf16*)p;                p += (long)H * S * HD * 2;
    bf16* Vt      = (bf16*)p;                p += (long)H * HD * S * 2;
    bf16* emb_bf  = (bf16*)p;                p += (long)V * D * 2;
    bf16* qkvW_bf = (bf16*)p;                p += (long)NLAYERS * 3 * D * D * 2;
    bf16* outW_bf = (bf16*)p;                p += (long)NLAYERS * D * D * 2;
    bf16* fc1W_bf = (bf16*)p;                p += (long)NLAYERS * 2 * DFF * D * 2;
    bf16* fc2W_bf = (bf16*)p;                p += (long)NLAYERS * D * DFF * 2;

    // ---- weight prep (LoRA fold) ----
    k_fold<<<dim3(D / 256, 3 * D / 8, NLAYERS), 256, 0, stream>>>(qkv_W, qkv_A, qkv_B, qkvW_bf, 3 * D, D);
    k_fold<<<dim3(D / 256, D / 8, NLAYERS), 256, 0, stream>>>(out_W, out_A, out_B, outW_bf, D, D);
    k_fold<<<dim3(D / 256, 2 * DFF / 8, NLAYERS), 256, 0, stream>>>(fc1_W, fc1_A, fc1_B, fc1W_bf, 2 * DFF, D);
    k_fold<<<dim3(DFF / 256, D / 8, NLAYERS), 256, 0, stream>>>(fc2_W, fc2_A, fc2_B, fc2W_bf, D, DFF);
    {
        long n = (long)V * D;
        k_cvt<<<(n / 4 + 255) / 256, 256, 0, stream>>>(emb, emb_bf, n);
    }

    k_embed<<<S, 256, 0, stream>>>(ids, emb, x);

    const int NWG_QKV = (S / 64) * (3 * D / 128);   // 576
    const int NWG_FC1 = (S / 64) * (DFF / 128);     // 768
    const int NWG_SM  = (S / 32) * (D / 128);       // 384
    const int NWG_LM  = (V / 128) * 16;             // 4000

    for (int l = 0; l < NLAYERS; l++) {
        // ---- attention block ----
        k_ln_bf<<<S / 4, 256, 0, stream>>>(x, ln1_g + l * D, ln1_b + l * D, h_bf);
        k_gemm_qkv<<<NWG_QKV, 256, 0, stream>>>(h_bf, qkvW_bf + (long)l * 3 * D * D, Qh, Kh, Vt, NWG_QKV);
        k_attn_mfma<<<dim3(S / 64, H), 256, 0, stream>>>(Qh, Kh, Vt, slopes, ao_bf);
        k_gemm_small<1><<<NWG_SM, 256, 0, stream>>>(ao_bf, outW_bf + (long)l * D * D, x, D, D, ls1 + l * D, NWG_SM);

        // ---- FFN block ----
        k_ln_bf<<<S / 4, 256, 0, stream>>>(x, ln2_g + l * D, ln2_b + l * D, h_bf);
        k_gemm_fc1<<<NWG_FC1, 256, 0, stream>>>(h_bf, fc1W_bf + (long)l * 2 * DFF * D, hid_bf, NWG_FC1);
        k_gemm_small<2><<<NWG_SM, 256, 0, stream>>>(hid_bf, fc2W_bf + (long)l * D * DFF, x, D, DFF, ls2 + l * D, NWG_SM);
    }

    // ---- final LN + tied lm_head (dbuf prefetch-ahead) ----
    k_ln_bf<<<S / 4, 256, 0, stream>>>(x, lnf_g, lnf_b, h_bf);
    k_gemm_lm<<<NWG_LM, 256, 0, stream>>>(h_bf, emb_bf, (float*)d_out, V, D, NWG_LM);
}

// Round 19
// 1019.473 us; speedup vs baseline: 1.0209x; 1.0209x over previous
//
#include <hip/hip_runtime.h>
#include <hip/hip_bf16.h>
#include <stdint.h>

#define S 2048
#define D 768
#define H 12
#define HD 64
#define V 32000
#define R 32
#define DFF 3072
#define NLAYERS 4
#define EPS 1e-6f

typedef __bf16 bf16;
typedef __bf16 bf16x4 __attribute__((ext_vector_type(4)));
typedef __bf16 bf16x8 __attribute__((ext_vector_type(8)));
typedef float f32x4 __attribute__((ext_vector_type(4)));

// 1D grid, XCD-bijective swizzle (nwg % 8 == 0 for all grids), M-fastest so
// consecutive logical blocks share one B-panel (L2 reuse).
__device__ __forceinline__ int swz_logical(int nwg) {
    int id = blockIdx.x;
    int q = nwg >> 3;
    return (id & 7) * q + (id >> 3);
}

// ---------------- fp32 -> bf16 conversion ----------------
__global__ __launch_bounds__(256) void k_cvt(const float* __restrict__ in,
                                             bf16* __restrict__ out, long n) {
    long i = ((long)blockIdx.x * 256 + threadIdx.x) * 4;
    if (i >= n) return;
    float4 v = *(const float4*)(in + i);
    bf16x4 o;
    o.x = (bf16)v.x; o.y = (bf16)v.y; o.z = (bf16)v.z; o.w = (bf16)v.w;
    *(bf16x4*)(out + i) = o;
}

// ---- LoRA fold (A staged in LDS): Wb[n,k] = bf16(W[n,k] + (1/R)*sum_r A[k,r]*B[r,n])
__global__ __launch_bounds__(256) void k_fold(const float* __restrict__ W,
                                              const float* __restrict__ A,
                                              const float* __restrict__ B,
                                              bf16* __restrict__ Wb,
                                              int N, int K) {
    __shared__ float As[256][33];   // [k_local][r], +1 pad
    int l = blockIdx.z;
    const float* Wl = W + (long)l * N * K;
    const float* Al = A + (long)l * K * R;
    const float* Bl = B + (long)l * R * N;
    bf16* Wbl = Wb + (long)l * N * K;
    int t = threadIdx.x;
    long k0 = (long)blockIdx.x * 256;
    int n0 = blockIdx.y * 8;
    const float* Ab = Al + k0 * R;
    #pragma unroll
    for (int i = 0; i < 32; ++i) {
        int idx = i * 256 + t;
        As[idx >> 5][idx & 31] = Ab[idx];
    }
    __syncthreads();
    long k = k0 + t;
    float acc[8];
    #pragma unroll
    for (int j = 0; j < 8; ++j) acc[j] = Wl[(long)(n0 + j) * K + k];
    for (int r = 0; r < R; ++r) {
        float a = As[t][r] * (1.0f / R);
        #pragma unroll
        for (int j = 0; j < 8; ++j)
            acc[j] = fmaf(a, Bl[(long)r * N + n0 + j], acc[j]);
    }
    #pragma unroll
    for (int j = 0; j < 8; ++j) Wbl[(long)(n0 + j) * K + k] = (bf16)acc[j];
}

// ---------------- embedding gather ----------------
__global__ void k_embed(const int* __restrict__ ids, const float* __restrict__ emb,
                        float* __restrict__ x) {
    int s = blockIdx.x;
    int row = ids[s];
    for (int d = threadIdx.x; d < D; d += blockDim.x)
        x[s * D + d] = emb[row * D + d];
}

// ---------------- layernorm -> bf16, one WAVE per row, no barriers ----------
__global__ __launch_bounds__(256) void k_ln_bf(const float* __restrict__ x,
                                               const float* __restrict__ g,
                                               const float* __restrict__ b,
                                               bf16* __restrict__ out) {
    int w = threadIdx.x >> 6, lane = threadIdx.x & 63;
    long s = (long)blockIdx.x * 4 + w;
    const float* xr = x + s * D;
    float4 v0 = *(const float4*)(xr + lane * 4);
    float4 v1 = *(const float4*)(xr + 256 + lane * 4);
    float4 v2 = *(const float4*)(xr + 512 + lane * 4);
    float sum = v0.x + v0.y + v0.z + v0.w + v1.x + v1.y + v1.z + v1.w
              + v2.x + v2.y + v2.z + v2.w;
    float sq = v0.x*v0.x + v0.y*v0.y + v0.z*v0.z + v0.w*v0.w
             + v1.x*v1.x + v1.y*v1.y + v1.z*v1.z + v1.w*v1.w
             + v2.x*v2.x + v2.y*v2.y + v2.z*v2.z + v2.w*v2.w;
    #pragma unroll
    for (int m = 1; m < 64; m <<= 1) {
        sum += __shfl_xor(sum, m);
        sq  += __shfl_xor(sq, m);
    }
    float mean = sum * (1.0f / D);
    float var  = sq * (1.0f / D) - mean * mean;
    float rs = rsqrtf(var + EPS);
    bf16* orow = out + s * D;
    #pragma unroll
    for (int j = 0; j < 3; ++j) {
        float4 v = (j == 0) ? v0 : (j == 1) ? v1 : v2;
        float4 gv = *(const float4*)(g + j * 256 + lane * 4);
        float4 bv = *(const float4*)(b + j * 256 + lane * 4);
        bf16x4 o;
        o[0] = (bf16)((v.x - mean) * rs * gv.x + bv.x);
        o[1] = (bf16)((v.y - mean) * rs * gv.y + bv.y);
        o[2] = (bf16)((v.z - mean) * rs * gv.z + bv.z);
        o[3] = (bf16)((v.w - mean) * rs * gv.w + bv.w);
        *(bf16x4*)(orow + j * 256 + lane * 4) = o;
    }
}

// ---------------- shared GEMM machinery ----------------
__device__ __forceinline__ void gload16(const bf16* g, bf16* l) {
    __builtin_amdgcn_global_load_lds(
        (const __attribute__((address_space(1))) void*)g,
        (__attribute__((address_space(3))) void*)l, 16, 0, 0);
}

// lm_head GEMM: 128x128 tile, BK=32, conflict-free swizzle + T3-min
// prefetch-ahead double buffer (r16-proven: 162us, occ 39%, 0 conflicts).
__global__ __launch_bounds__(256) void k_gemm_lm(const bf16* __restrict__ X,
                                                 const bf16* __restrict__ W,
                                                 float* __restrict__ C,
                                                 int N, int K, int nwg) {
    __shared__ bf16 At[2][128 * 32];
    __shared__ bf16 Bt[2][128 * 32];
    int tid = threadIdx.x;
    int w = tid >> 6, lane = tid & 63;
    int logical = swz_logical(nwg);
    long m0 = (long)(logical & 15) * 128;
    long n0 = (long)(logical >> 4) * 128;
    int wr = (w >> 1) * 64, wc = (w & 1) * 64;
    int fr = lane & 15;
    int g  = lane >> 4;
    f32x4 acc[4][4] = {};

#define STAGE_LM(K0, BUF) do {                                             \
    _Pragma("unroll")                                                      \
    for (int i = 0; i < 2; ++i) {                                          \
        int ci = tid + 256 * i;                                            \
        int r = ci >> 2, c = (ci & 3) ^ ((r >> 1) & 3);                    \
        gload16(X + (m0 + r) * K + (K0) + c * 8, At[BUF] + ci * 8);        \
        gload16(W + (n0 + r) * K + (K0) + c * 8, Bt[BUF] + ci * 8);        \
    } } while (0)

    STAGE_LM(0, 0);
    __syncthreads();
    int cur = 0;
    for (int k0 = 0; k0 < K; k0 += 32) {
        if (k0 + 32 < K) STAGE_LM(k0 + 32, cur ^ 1);
        bf16x8 a[4], b[4];
        #pragma unroll
        for (int m = 0; m < 4; m++) {
            int row = wr + m * 16 + fr;
            a[m] = *(const bf16x8*)(At[cur] + row * 32 + ((g ^ ((row >> 1) & 3)) * 8));
        }
        #pragma unroll
        for (int n = 0; n < 4; n++) {
            int row = wc + n * 16 + fr;
            b[n] = *(const bf16x8*)(Bt[cur] + row * 32 + ((g ^ ((row >> 1) & 3)) * 8));
        }
        #pragma unroll
        for (int m = 0; m < 4; m++)
            #pragma unroll
            for (int n = 0; n < 4; n++)
                acc[m][n] = __builtin_amdgcn_mfma_f32_16x16x32_bf16(a[m], b[n], acc[m][n], 0, 0, 0);
        __syncthreads();
        cur ^= 1;
    }
#undef STAGE_LM
    int cr = (lane >> 4) * 4, cc = lane & 15;
    #pragma unroll
    for (int m = 0; m < 4; m++)
        #pragma unroll
        for (int n = 0; n < 4; n++) {
            long col = n0 + wc + n * 16 + cc;
            #pragma unroll
            for (int r = 0; r < 4; r++) {
                long idx = (m0 + wr + m * 16 + cr + r) * N + col;
                C[idx] = acc[m][n][r];
            }
        }
}

// 32x128 tile small-N GEMM (out-proj, fc2): r15-proven single-buffer config
// (384 blocks, BK=64 XOR swizzle, 20 KB LDS -> 8 blocks/CU). Always RESID.
template <int TAG>
__global__ __launch_bounds__(256) void k_gemm_small(const bf16* __restrict__ X,
                                                    const bf16* __restrict__ W,
                                                    float* __restrict__ C,
                                                    int N, int K,
                                                    const float* __restrict__ ls,
                                                    int nwg) {
    __shared__ bf16 At[32 * 64];        // 4 KB
    __shared__ bf16 Bt[128 * 64];       // 16 KB
    int tid = threadIdx.x;
    int w = tid >> 6, lane = tid & 63;
    int logical = swz_logical(nwg);
    long m0 = (long)(logical & 63) * 32;
    long n0 = (long)(logical >> 6) * 128;
    int wr = (w >> 1) * 16, wc = (w & 1) * 64;
    int fr = lane & 15;
    int g  = lane >> 4;
    f32x4 acc[4] = {};
    for (int k0 = 0; k0 < K; k0 += 64) {
        {
            int ci = tid;
            int r = ci >> 3, c = (ci & 7) ^ (r & 7);
            gload16(X + (m0 + r) * K + k0 + c * 8, At + ci * 8);
        }
        #pragma unroll
        for (int i = 0; i < 4; ++i) {
            int ci = tid + 256 * i;
            int r = ci >> 3, c = (ci & 7) ^ (r & 7);
            gload16(W + (n0 + r) * K + k0 + c * 8, Bt + ci * 8);
        }
        __syncthreads();
        #pragma unroll
        for (int kk = 0; kk < 2; ++kk) {
            bf16x8 a, b[4];
            {
                int row = wr + fr;
                a = *(const bf16x8*)(At + row * 64 + (((kk * 4 + g) ^ (row & 7)) * 8));
            }
            #pragma unroll
            for (int n = 0; n < 4; n++) {
                int row = wc + n * 16 + fr;
                b[n] = *(const bf16x8*)(Bt + row * 64 + (((kk * 4 + g) ^ (row & 7)) * 8));
            }
            #pragma unroll
            for (int n = 0; n < 4; n++)
                acc[n] = __builtin_amdgcn_mfma_f32_16x16x32_bf16(a, b[n], acc[n], 0, 0, 0);
        }
        __syncthreads();
    }
    int cr = (lane >> 4) * 4, cc = lane & 15;
    #pragma unroll
    for (int n = 0; n < 4; n++) {
        long col = n0 + wc + n * 16 + cc;
        #pragma unroll
        for (int r = 0; r < 4; r++) {
            long idx = (m0 + wr + cr + r) * N + col;
            C[idx] = fmaf(ls[col], acc[n][r], C[idx]);
        }
    }
}

// qkv GEMM, 64x128 tile, BK=64 swizzled, single-buffer (r13-proven), fused
// Q/K/Vt split epilogue overlaying the 24KB staging LDS.
__global__ __launch_bounds__(256) void k_gemm_qkv(const bf16* __restrict__ X,
                                                  const bf16* __restrict__ W,
                                                  bf16* __restrict__ Qh,
                                                  bf16* __restrict__ Kh,
                                                  bf16* __restrict__ Vt,
                                                  int nwg) {
    const int K = D;
    __shared__ bf16 smem[64 * 64 + 128 * 64];   // 24 KB
    bf16* At = smem;
    bf16* Bt = smem + 64 * 64;
    int tid = threadIdx.x;
    int w = tid >> 6, lane = tid & 63;
    int logical = swz_logical(nwg);
    long m0 = (long)(logical & 31) * 64;
    long n0 = (long)(logical >> 5) * 128;
    int wr = (w >> 1) * 32, wc = (w & 1) * 64;
    int fr = lane & 15;
    int g  = lane >> 4;
    f32x4 acc[2][4] = {};
    for (int k0 = 0; k0 < K; k0 += 64) {
        #pragma unroll
        for (int i = 0; i < 2; ++i) {
            int ci = tid + 256 * i;
            int r = ci >> 3, c = (ci & 7) ^ (r & 7);
            gload16(X + (m0 + r) * K + k0 + c * 8, At + ci * 8);
        }
        #pragma unroll
        for (int i = 0; i < 4; ++i) {
            int ci = tid + 256 * i;
            int r = ci >> 3, c = (ci & 7) ^ (r & 7);
            gload16(W + (n0 + r) * K + k0 + c * 8, Bt + ci * 8);
        }
        __syncthreads();
        #pragma unroll
        for (int kk = 0; kk < 2; ++kk) {
            bf16x8 a[2], b[4];
            #pragma unroll
            for (int m = 0; m < 2; m++) {
                int row = wr + m * 16 + fr;
                a[m] = *(const bf16x8*)(At + row * 64 + (((kk * 4 + g) ^ (row & 7)) * 8));
            }
            #pragma unroll
            for (int n = 0; n < 4; n++) {
                int row = wc + n * 16 + fr;
                b[n] = *(const bf16x8*)(Bt + row * 64 + (((kk * 4 + g) ^ (row & 7)) * 8));
            }
            #pragma unroll
            for (int m = 0; m < 2; m++)
                #pragma unroll
                for (int n = 0; n < 4; n++)
                    acc[m][n] = __builtin_amdgcn_mfma_f32_16x16x32_bf16(a[m], b[n], acc[m][n], 0, 0, 0);
        }
        __syncthreads();
    }
    int cr = (lane >> 4) * 4, cc = lane & 15;
    if (n0 < 1536) {
        // ---- Q or K: stage [s][col] in LDS ([64][136]), coalesced store ----
        float scale = (n0 < 768) ? 0.125f : 1.0f;
        bf16* dst = (n0 < 768) ? Qh : Kh;
        int base = (n0 < 768) ? (int)n0 : (int)n0 - 768;
        #pragma unroll
        for (int m = 0; m < 2; m++)
            #pragma unroll
            for (int n = 0; n < 4; n++)
                #pragma unroll
                for (int r = 0; r < 4; r++)
                    smem[(wr + m * 16 + cr + r) * 136 + wc + n * 16 + cc] =
                        (bf16)(acc[m][n][r] * scale);
        __syncthreads();
        #pragma unroll
        for (int i = 0; i < 4; ++i) {       // 1024 chunks of bf16x8
            int c = tid + 256 * i;
            int srow = c >> 4, off = (c & 15) * 8;
            int hh = (base >> 6) + (off >> 6);
            int d0 = off & 63;
            bf16x8 vv = *(const bf16x8*)(smem + srow * 136 + off);
            *(bf16x8*)(dst + ((long)hh * S + m0 + srow) * HD + d0) = vv;
        }
    } else {
        // ---- V: stage TRANSPOSED [col][s] in LDS ([128][72]), coalesced ----
        int base = (int)n0 - 1536;
        #pragma unroll
        for (int m = 0; m < 2; m++)
            #pragma unroll
            for (int n = 0; n < 4; n++) {
                bf16x4 pv;
                #pragma unroll
                for (int r = 0; r < 4; ++r) pv[r] = (bf16)acc[m][n][r];
                *(bf16x4*)(smem + (wc + n * 16 + cc) * 72 + wr + m * 16 + cr) = pv;
            }
        __syncthreads();
        #pragma unroll
        for (int i = 0; i < 4; ++i) {       // 1024 chunks of bf16x8
            int c = tid + 256 * i;
            int vcol = c >> 3, soff = (c & 7) * 8;
            bf16x8 vv = *(const bf16x8*)(smem + vcol * 72 + soff);
            *(bf16x8*)(Vt + (long)(base + vcol) * S + m0 + soff) = vv;
        }
    }
}

// fc1 GEMM, 64x128 tile, BK=64 swizzled, dual-B, fused SwiGLU (r13-proven).
__global__ __launch_bounds__(256) void k_gemm_fc1(const bf16* __restrict__ X,
                                                  const bf16* __restrict__ W,
                                                  bf16* __restrict__ hb,
                                                  int nwg) {
    const int K = D;
    __shared__ bf16 At[64 * 64];        // 8 KB
    __shared__ bf16 Bg[128 * 64];       // 16 KB
    __shared__ bf16 Ba[128 * 64];       // 16 KB
    int tid = threadIdx.x;
    int w = tid >> 6, lane = tid & 63;
    int logical = swz_logical(nwg);
    long m0 = (long)(logical & 31) * 64;
    long f0 = (long)(logical >> 5) * 128;
    int wr = (w >> 1) * 32, wc = (w & 1) * 64;
    int fr = lane & 15;
    int g  = lane >> 4;
    const bf16* Wg = W + f0 * K;
    const bf16* Wa = W + ((long)DFF + f0) * K;
    f32x4 accG[2][4] = {}, accA[2][4] = {};
    for (int k0 = 0; k0 < K; k0 += 64) {
        #pragma unroll
        for (int i = 0; i < 2; ++i) {
            int ci = tid + 256 * i;
            int r = ci >> 3, c = (ci & 7) ^ (r & 7);
            gload16(X + (m0 + r) * K + k0 + c * 8, At + ci * 8);
        }
        #pragma unroll
        for (int i = 0; i < 4; ++i) {
            int ci = tid + 256 * i;
            int r = ci >> 3, c = (ci & 7) ^ (r & 7);
            gload16(Wg + (long)r * K + k0 + c * 8, Bg + ci * 8);
            gload16(Wa + (long)r * K + k0 + c * 8, Ba + ci * 8);
        }
        __syncthreads();
        #pragma unroll
        for (int kk = 0; kk < 2; ++kk) {
            bf16x8 a[2], bg[4], ba[4];
            #pragma unroll
            for (int m = 0; m < 2; m++) {
                int row = wr + m * 16 + fr;
                a[m] = *(const bf16x8*)(At + row * 64 + (((kk * 4 + g) ^ (row & 7)) * 8));
            }
            #pragma unroll
            for (int n = 0; n < 4; n++) {
                int row = wc + n * 16 + fr;
                int off = row * 64 + (((kk * 4 + g) ^ (row & 7)) * 8);
                bg[n] = *(const bf16x8*)(Bg + off);
                ba[n] = *(const bf16x8*)(Ba + off);
            }
            #pragma unroll
            for (int m = 0; m < 2; m++)
                #pragma unroll
                for (int n = 0; n < 4; n++) {
                    accG[m][n] = __builtin_amdgcn_mfma_f32_16x16x32_bf16(a[m], bg[n], accG[m][n], 0, 0, 0);
                    accA[m][n] = __builtin_amdgcn_mfma_f32_16x16x32_bf16(a[m], ba[n], accA[m][n], 0, 0, 0);
                }
        }
        __syncthreads();
    }
    int cr = (lane >> 4) * 4, cc = lane & 15;
    #pragma unroll
    for (int m = 0; m < 2; m++)
        #pragma unroll
        for (int n = 0; n < 4; n++) {
            long col = f0 + wc + n * 16 + cc;
            #pragma unroll
            for (int r = 0; r < 4; r++) {
                long s = m0 + wr + m * 16 + cr + r;
                float gv = accG[m][n][r], av = accA[m][n][r];
                float sig = 1.0f / (1.0f + __expf(-gv));
                hb[s * DFF + col] = (bf16)(gv * sig * av);
            }
        }
}

// ---------------- flash attention, MFMA, ALiBi+causal (round-7 proven) -----
__global__ __launch_bounds__(256) void k_attn_mfma(const bf16* __restrict__ Qh,
                                                   const bf16* __restrict__ Kh,
                                                   const bf16* __restrict__ Vt,
                                                   const float* __restrict__ slopes,
                                                   bf16* __restrict__ ao) {
    __shared__ bf16 Kl[128 * 64];
    __shared__ bf16 Vl[64 * 128];
    __shared__ bf16 Pl[4][16 * 136];
    int tid = threadIdx.x;
    int w = tid >> 6, lane = tid & 63;
    int fr = lane & 15, g = lane >> 4;
    int qb = gridDim.x - 1 - blockIdx.x;
    int q0 = qb * 64;
    int h = blockIdx.y;
    int ntiles = qb / 2 + 1;
    float slope = slopes[h];

    const bf16* qrow = Qh + ((long)h * S + q0 + w * 16 + fr) * HD;
    bf16x8 qf0 = *(const bf16x8*)(qrow + g * 8);
    bf16x8 qf1 = *(const bf16x8*)(qrow + 32 + g * 8);

    const bf16* Kg = Kh + (long)h * S * HD;
    const bf16* Vg = Vt + (long)h * HD * S;

    float m = -1e9f, l = 0.f;
    f32x4 o[4] = {};
    int qg = q0 + w * 16 + fr;

    for (int t = 0; t < ntiles; ++t) {
        int j0 = t * 128;
        __syncthreads();
        #pragma unroll
        for (int i = 0; i < 4; ++i) {
            int ci = tid + 256 * i;
            int r = ci >> 3, c = (ci & 7) ^ (r & 7);
            gload16(Kg + (long)(j0 + r) * HD + c * 8, Kl + ci * 8);
        }
        #pragma unroll
        for (int i = 0; i < 4; ++i) {
            int ci = tid + 256 * i;
            int rd = ci >> 4, cj = (ci & 15) ^ (rd & 7);
            gload16(Vg + (long)rd * S + j0 + cj * 8, Vl + ci * 8);
        }
        __syncthreads();

        f32x4 sc[8];
        __builtin_amdgcn_s_setprio(1);
        #pragma unroll
        for (int jt = 0; jt < 8; ++jt) {
            int jr = jt * 16 + fr;
            bf16x8 kf0 = *(const bf16x8*)(Kl + jr * 64 + ((g ^ (jr & 7)) * 8));
            bf16x8 kf1 = *(const bf16x8*)(Kl + jr * 64 + (((g + 4) ^ (jr & 7)) * 8));
            f32x4 z = {};
            z = __builtin_amdgcn_mfma_f32_16x16x32_bf16(kf0, qf0, z, 0, 0, 0);
            z = __builtin_amdgcn_mfma_f32_16x16x32_bf16(kf1, qf1, z, 0, 0, 0);
            sc[jt] = z;
        }
        __builtin_amdgcn_s_setprio(0);

        bool need_mask = (j0 + 127) > (q0 + w * 16);
        float mt = -1e9f;
        if (need_mask) {
            #pragma unroll
            for (int jt = 0; jt < 8; ++jt)
                #pragma unroll
                for (int r = 0; r < 4; ++r) {
                    int rel = (j0 + jt * 16 + g * 4 + r) - qg;
                    float v = (rel <= 0) ? fmaf(slope, (float)rel, sc[jt][r]) : -1e9f;
                    sc[jt][r] = v;
                    mt = fmaxf(mt, v);
                }
        } else {
            #pragma unroll
            for (int jt = 0; jt < 8; ++jt)
                #pragma unroll
                for (int r = 0; r < 4; ++r) {
                    int rel = (j0 + jt * 16 + g * 4 + r) - qg;
                    float v = fmaf(slope, (float)rel, sc[jt][r]);
                    sc[jt][r] = v;
                    mt = fmaxf(mt, v);
                }
        }
        mt = fmaxf(mt, __shfl_xor(mt, 16));
        mt = fmaxf(mt, __shfl_xor(mt, 32));
        float mnew = fmaxf(m, mt);
        float factor = __expf(m - mnew);
        float psum = 0.f;
        #pragma unroll
        for (int jt = 0; jt < 8; ++jt) {
            bf16x4 pb;
            #pragma unroll
            for (int r = 0; r < 4; ++r) {
                float p = __expf(sc[jt][r] - mnew);
                psum += p;
                pb[r] = (bf16)p;
            }
            *(bf16x4*)(&Pl[w][fr * 136 + jt * 16 + g * 4]) = pb;
        }
        psum += __shfl_xor(psum, 16);
        psum += __shfl_xor(psum, 32);
        l = l * factor + psum;
        m = mnew;
        #pragma unroll
        for (int dt = 0; dt < 4; ++dt)
            #pragma unroll
            for (int r = 0; r < 4; ++r) o[dt][r] *= factor;

        bf16x8 pf[4];
        #pragma unroll
        for (int ks = 0; ks < 4; ++ks)
            pf[ks] = *(const bf16x8*)(&Pl[w][fr * 136 + ks * 32 + g * 8]);
        __builtin_amdgcn_s_setprio(1);
        #pragma unroll
        for (int dt = 0; dt < 4; ++dt) {
            int dr = dt * 16 + fr;
            #pragma unroll
            for (int ks = 0; ks < 4; ++ks) {
                bf16x8 vf = *(const bf16x8*)(Vl + dr * 128 + (((ks * 4 + g) ^ (dr & 7)) * 8));
                o[dt] = __builtin_amdgcn_mfma_f32_16x16x32_bf16(vf, pf[ks], o[dt], 0, 0, 0);
            }
        }
        __builtin_amdgcn_s_setprio(0);
    }
    float inv = 1.0f / l;
    bf16* orow = ao + ((long)(q0 + w * 16 + fr)) * D + h * HD;
    #pragma unroll
    for (int dt = 0; dt < 4; ++dt) {
        bf16x4 ob;
        #pragma unroll
        for (int r = 0; r < 4; ++r) ob[r] = (bf16)(o[dt][r] * inv);
        *(bf16x4*)(orow + dt * 16 + g * 4) = ob;
    }
}

extern "C" void kernel_launch(void* const* d_in, const int* in_sizes, int n_in,
                              void* d_out, int out_size, void* d_ws, size_t ws_size,
                              hipStream_t stream) {
    const int*   ids    = (const int*)d_in[0];
    const float* emb    = (const float*)d_in[1];
    const float* slopes = (const float*)d_in[2];
    const float* ln1_g  = (const float*)d_in[3];
    const float* ln1_b  = (const float*)d_in[4];
    const float* qkv_W  = (const float*)d_in[5];
    const float* qkv_A  = (const float*)d_in[6];
    const float* qkv_B  = (const float*)d_in[7];
    const float* out_W  = (const float*)d_in[8];
    const float* out_A  = (const float*)d_in[9];
    const float* out_B  = (const float*)d_in[10];
    const float* ln2_g  = (const float*)d_in[11];
    const float* ln2_b  = (const float*)d_in[12];
    const float* fc1_W  = (const float*)d_in[13];
    const float* fc1_A  = (const float*)d_in[14];
    const float* fc1_B  = (const float*)d_in[15];
    const float* fc2_W  = (const float*)d_in[16];
    const float* fc2_A  = (const float*)d_in[17];
    const float* fc2_B  = (const float*)d_in[18];
    const float* ls1    = (const float*)d_in[19];
    const float* ls2    = (const float*)d_in[20];
    const float* lnf_g  = (const float*)d_in[21];
    const float* lnf_b  = (const float*)d_in[22];

    // ---- workspace layout ----
    char* p = (char*)d_ws;
    float* x      = (float*)p;               p += (long)S * D * 4;
    bf16* h_bf    = (bf16*)p;                p += (long)S * D * 2;
    bf16* ao_bf   = (bf16*)p;                p += (long)S * D * 2;
    bf16* hid_bf  = (bf16*)p;                p += (long)S * DFF * 2;
    bf16* Qh      = (bf16*)p;                p += (long)H * S * HD * 2;
    bf16* Kh      = (bf16*)p;                p += (long)H * S * HD * 2;
    bf16* Vt      = (bf16*)p;                p += (long)H * HD * S * 2;
    bf16* emb_bf  = (bf16*)p;                p += (long)V * D * 2;
    bf16* qkvW_bf = (bf16*)p;                p += (long)NLAYERS * 3 * D * D * 2;
    bf16* outW_bf = (bf16*)p;                p += (long)NLAYERS * D * D * 2;
    bf16* fc1W_bf = (bf16*)p;                p += (long)NLAYERS * 2 * DFF * D * 2;
    bf16* fc2W_bf = (bf16*)p;                p += (long)NLAYERS * D * DFF * 2;

    // ---- weight prep (LoRA fold) ----
    k_fold<<<dim3(D / 256, 3 * D / 8, NLAYERS), 256, 0, stream>>>(qkv_W, qkv_A, qkv_B, qkvW_bf, 3 * D, D);
    k_fold<<<dim3(D / 256, D / 8, NLAYERS), 256, 0, stream>>>(out_W, out_A, out_B, outW_bf, D, D);
    k_fold<<<dim3(D / 256, 2 * DFF / 8, NLAYERS), 256, 0, stream>>>(fc1_W, fc1_A, fc1_B, fc1W_bf, 2 * DFF, D);
    k_fold<<<dim3(DFF / 256, D / 8, NLAYERS), 256, 0, stream>>>(fc2_W, fc2_A, fc2_B, fc2W_bf, D, DFF);
    {
        long n = (long)V * D;
        k_cvt<<<(n / 4 + 255) / 256, 256, 0, stream>>>(emb, emb_bf, n);
    }

    k_embed<<<S, 256, 0, stream>>>(ids, emb, x);

    const int NWG_QKV = (S / 64) * (3 * D / 128);   // 576
    const int NWG_FC1 = (S / 64) * (DFF / 128);     // 768
    const int NWG_SM  = (S / 32) * (D / 128);       // 384
    const int NWG_LM  = (V / 128) * 16;             // 4000

    for (int l = 0; l < NLAYERS; l++) {
        // ---- attention block ----
        k_ln_bf<<<S / 4, 256, 0, stream>>>(x, ln1_g + l * D, ln1_b + l * D, h_bf);
        k_gemm_qkv<<<NWG_QKV, 256, 0, stream>>>(h_bf, qkvW_bf + (long)l * 3 * D * D, Qh, Kh, Vt, NWG_QKV);
        k_attn_mfma<<<dim3(S / 64, H), 256, 0, stream>>>(Qh, Kh, Vt, slopes, ao_bf);
        k_gemm_small<1><<<NWG_SM, 256, 0, stream>>>(ao_bf, outW_bf + (long)l * D * D, x, D, D, ls1 + l * D, NWG_SM);

        // ---- FFN block ----
        k_ln_bf<<<S / 4, 256, 0, stream>>>(x, ln2_g + l * D, ln2_b + l * D, h_bf);
        k_gemm_fc1<<<NWG_FC1, 256, 0, stream>>>(h_bf, fc1W_bf + (long)l * 2 * DFF * D, hid_bf, NWG_FC1);
        k_gemm_small<2><<<NWG_SM, 256, 0, stream>>>(hid_bf, fc2W_bf + (long)l * D * DFF, x, D, DFF, ls2 + l * D, NWG_SM);
    }

    // ---- final LN + tied lm_head (dbuf prefetch-ahead) ----
    k_ln_bf<<<S / 4, 256, 0, stream>>>(x, lnf_g, lnf_b, h_bf);
    k_gemm_lm<<<NWG_LM, 256, 0, stream>>>(h_bf, emb_bf, (float*)d_out, V, D, NWG_LM);
}